// Round 2
// 420.971 us; speedup vs baseline: 1.0035x; 1.0035x over previous
//
#include <hip/hip_runtime.h>
#include <hip/hip_bf16.h>

// ---------------------------------------------------------------------------
// Set2Set pooling: 3 steps of { LSTM cell -> fused segment softmax attention }
// then a final projection.  B=256 graphs, N=100000 nodes, d=512.
//
// Round-7 structure:
//   prep      : W_ih|W_hh -> Wcat bf16 [2048][1536]; W_proj -> bf16; bias sums f32
//   lstm0     : step-0 LSTM specialization (gates = b_ih+b_hh, c=0 analytically)
//   attn step0: flash-style softmax-attention pass over x (fp32), fused cast of
//               x -> xb (bf16) for later steps; r -> Abuf0
//   gemm_lstm : gates GEMM (MFMA bf16, 4 gate tiles per block) with the LSTM
//               pointwise fused in the epilogue; h -> h_buf + AbufOut (ping-pong)
//   attn 1,2  : read xb (bf16)
//   proj      : out = q_star @ W_proj^T + b_proj
//
// Round-7 change (re-run; round-1 bench was an infra flake): attention_kernel
// is templated on host-known <STEP0, USE_XB> and the device-only fp32 flag is
// hand-unswitched into two BRANCH-FREE loops (fp32+fused-cast vs bf16), each
// processing 4 rows per wave-iteration with a single predicated tail.
// Rationale: runtime-uniform branches + per-iteration tail checks inside the
// hot loop were blocking load pipelining / memory-level parallelism.
// ---------------------------------------------------------------------------

typedef __bf16 bf16_t;
typedef __bf16 bf16x8 __attribute__((ext_vector_type(8)));
typedef float  f32x4  __attribute__((ext_vector_type(4)));

#define D     512
#define B_GR  256
#define FOURD 2048
#define KCAT  1536
#define AWAVES 16     // waves per attention block (1024 threads)
#define DET_BLOCKS 400

// ---------------------------------------------------------------------------
__device__ __forceinline__ float load_f(const void* b, int i, int f32) {
    return f32 ? ((const float*)b)[i] : (float)((const bf16_t*)b)[i];
}

// ---------------------------------------------------------------------------
// Stage 1: per-block detection partials (every slot written -> no init needed)
__global__ void detect_part1(const int* __restrict__ b32, int N,
                             const unsigned short* __restrict__ xh,
                             int* __restrict__ partA, int* __restrict__ partB) {
    __shared__ int sA, sB;
    if (threadIdx.x == 0) { sA = 0; sB = 0; }
    __syncthreads();
    int gid = blockIdx.x * blockDim.x + threadIdx.x;
    int stride = gridDim.x * blockDim.x;
    int dec = 0;
    for (int i = gid; i < N - 1; i += stride)
        if (b32[i] > b32[i + 1]) dec = 1;       // int64-as-int32 signature
    int bad = 0;
    for (int i = gid; i < 1024; i += stride) {
        unsigned e = (xh[i] >> 7) & 0xff;        // bf16 exponent field
        if (e >= 134) bad = 1;                   // fp32-bits-as-bf16 signature
    }
    if (dec) atomicOr(&sA, 1);
    if (bad) atomicOr(&sB, 1);
    __syncthreads();
    if (threadIdx.x == 0) { partA[blockIdx.x] = sA; partB[blockIdx.x] = sB; }
}

// Stage 2: OR-reduce partials, plain-store flags (flags[0]=int64, [1]=fp32).
__global__ void detect_part2(const int* __restrict__ partA,
                             const int* __restrict__ partB, int nblk,
                             int* __restrict__ flags) {
    __shared__ int sA, sB;
    if (threadIdx.x == 0) { sA = 0; sB = 0; }
    __syncthreads();
    int a = 0, b = 0;
    for (int i = threadIdx.x; i < nblk; i += blockDim.x) {
        a |= partA[i];
        b |= partB[i];
    }
    if (a) atomicOr(&sA, 1);
    if (b) atomicOr(&sB, 1);
    __syncthreads();
    if (threadIdx.x == 0) { flags[0] = sA; flags[1] = sB; }
}

// ---------------------------------------------------------------------------
// segment boundaries from sorted batch ids; seg[0..B] fully written every call
__global__ void seg_bounds_kernel(const void* __restrict__ batch, int N, int B,
                                  const int* __restrict__ flags,
                                  int* __restrict__ seg) {
    int n = blockIdx.x * blockDim.x + threadIdx.x;
    if (n >= N) return;
    const int is64 = flags[0];
    const int* b32 = (const int*)batch;
    const long long* b64 = (const long long*)batch;
    int cur = is64 ? (int)b64[n] : b32[n];
    if (n == 0) {
        for (int b = 0; b <= cur && b <= B; ++b) seg[b] = 0;
    } else {
        int prev = is64 ? (int)b64[n - 1] : b32[n - 1];
        for (int b = prev + 1; b <= cur && b <= B; ++b) seg[b] = n;
    }
    if (n == N - 1) {
        for (int b = cur + 1; b <= B; ++b) seg[b] = N;
    }
}

// ---------------------------------------------------------------------------
// Weight prep: Wcat[r][k] = k<1024 ? W_ih[r][k] : W_hh[r][k-1024] (bf16);
// Wp = W_proj bf16; bsum = b_ih+b_hh (f32); bp = b_proj (f32).
#define WCAT_E (FOURD * KCAT)
#define WP_E   (256 * 1024)
__global__ void prep_kernel(const void* __restrict__ W_ih,
                            const void* __restrict__ W_hh,
                            const void* __restrict__ b_ih,
                            const void* __restrict__ b_hh,
                            const void* __restrict__ W_proj,
                            const void* __restrict__ b_proj,
                            const int* __restrict__ flags,
                            bf16_t* __restrict__ Wcat, bf16_t* __restrict__ Wp,
                            float* __restrict__ bsum, float* __restrict__ bp) {
    const int f32 = flags[1];
    int gid = blockIdx.x * blockDim.x + threadIdx.x;
    int stride = gridDim.x * blockDim.x;
    const int total = WCAT_E + WP_E + FOURD + 256;
    for (int idx = gid; idx < total; idx += stride) {
        if (idx < WCAT_E) {
            int r = idx / KCAT, k = idx - r * KCAT;
            float v = (k < 1024) ? load_f(W_ih, r * 1024 + k, f32)
                                 : load_f(W_hh, r * 512 + (k - 1024), f32);
            Wcat[idx] = (bf16_t)v;
        } else if (idx < WCAT_E + WP_E) {
            int j = idx - WCAT_E;
            Wp[j] = (bf16_t)load_f(W_proj, j, f32);
        } else if (idx < WCAT_E + WP_E + FOURD) {
            int i = idx - WCAT_E - WP_E;
            bsum[i] = load_f(b_ih, i, f32) + load_f(b_hh, i, f32);
        } else {
            int i = idx - WCAT_E - WP_E - FOURD;
            bp[i] = load_f(b_proj, i, f32);
        }
    }
}

// ---------------------------------------------------------------------------
// Step-0 LSTM: gates = bsum, c_prev = 0 analytically.  Writes c, h, and h
// (bf16) into Abuf cols [0,512) and [1024,1536).
__global__ void lstm0_kernel(const float* __restrict__ bsum,
                             float* __restrict__ c, float* __restrict__ h,
                             bf16_t* __restrict__ Abuf) {
    int idx = blockIdx.x * blockDim.x + threadIdx.x;   // B*D threads
    int b = idx >> 9, t = idx & 511;
    float gi = bsum[t], gf = bsum[512 + t], gg = bsum[1024 + t], go = bsum[1536 + t];
    (void)gf;
    float si = 1.f / (1.f + __expf(-gi));
    float so = 1.f / (1.f + __expf(-go));
    float tg = tanhf(gg);
    float cn = si * tg;                 // sigmoid(f)*0 + sigmoid(i)*tanh(g)
    float hn = so * tanhf(cn);
    c[idx] = cn;
    h[idx] = hn;
    bf16_t hb = (bf16_t)hn;
    Abuf[(size_t)b * KCAT + t]        = hb;
    Abuf[(size_t)b * KCAT + 1024 + t] = hb;
}

// ---------------------------------------------------------------------------
// Fused gates-GEMM + LSTM pointwise.  One wave per (16 t-cols x 16 graphs);
// computes all 4 gate tiles (i,f,g,o) so the LSTM update happens in-register.
// Reads AbufIn (q_star||h), writes c (in-place), h_buf, and h->AbufOut.
__global__ __launch_bounds__(64)
void gemm_lstm(const bf16_t* __restrict__ AbufIn,
               const bf16_t* __restrict__ Wcat,
               const float* __restrict__ bsum,
               float* __restrict__ c, float* __restrict__ h,
               bf16_t* __restrict__ AbufOut) {
    const int lane  = threadIdx.x;
    const int t0    = blockIdx.x * 16;       // col within [0,512)
    const int m0    = blockIdx.y * 16;       // graph tile
    const int rowA  = m0 + (lane & 15);
    const int colB  = t0 + (lane & 15);
    const int kbase = (lane >> 4) * 8;

    f32x4 acc[4] = {{0,0,0,0},{0,0,0,0},{0,0,0,0},{0,0,0,0}};

    for (int k0 = 0; k0 < KCAT; k0 += 32) {
        int k = k0 + kbase;
        bf16x8 a = *(const bf16x8*)(AbufIn + (size_t)rowA * KCAT + k);
#pragma unroll
        for (int g = 0; g < 4; ++g) {
            bf16x8 bfr = *(const bf16x8*)(Wcat + (size_t)(g * 512 + colB) * KCAT + k);
            acc[g] = __builtin_amdgcn_mfma_f32_16x16x32_bf16(a, bfr, acc[g], 0, 0, 0);
        }
    }

    // D layout (verified m89): col = lane&15, row = (lane>>4)*4 + reg
    const int col   = colB;
    const int rbase = (lane >> 4) * 4;
    float bi = bsum[col], bf = bsum[512 + col], bg = bsum[1024 + col], bo = bsum[1536 + col];
#pragma unroll
    for (int r = 0; r < 4; ++r) {
        int m = m0 + rbase + r;
        float gi = acc[0][r] + bi;
        float gf = acc[1][r] + bf;
        float gg = acc[2][r] + bg;
        float go = acc[3][r] + bo;
        size_t ci = (size_t)m * D + col;
        float cv = c[ci];
        float si = 1.f / (1.f + __expf(-gi));
        float sf = 1.f / (1.f + __expf(-gf));
        float so = 1.f / (1.f + __expf(-go));
        float tg = tanhf(gg);
        float cn = sf * cv + si * tg;
        float hn = so * tanhf(cn);
        c[ci] = cn;
        h[ci] = hn;
        bf16_t hb = (bf16_t)hn;
        AbufOut[(size_t)m * KCAT + col]        = hb;
        AbufOut[(size_t)m * KCAT + 1024 + col] = hb;
    }
}

// ---------------------------------------------------------------------------
// Branch-free online-softmax scan bodies.  4 rows per wave-iteration, single
// predicated tail.  All lanes end with identical (m_w, s_w); r_w is per-lane.

// fp32 input, optional fused cast to xb (WRXB compile-time).
template<bool WRXB>
__device__ __forceinline__ void scan_f32(const float* __restrict__ xp,
                                         bf16_t* __restrict__ xb,
                                         int s, int cnt, int wave, int lane,
                                         const float* hl,
                                         float& m_w, float& s_w, float* r_w) {
    int i = 4 * wave;
    for (; i + 4 <= cnt; i += 4 * AWAVES) {
        size_t off = (((size_t)(s + i)) << 9) + (size_t)(lane * 8);
        float xr[4][8];
#pragma unroll
        for (int r = 0; r < 4; ++r) {
            const float* p = xp + off + (size_t)r * D;
            float4 v0 = *(const float4*)p;
            float4 v1 = *(const float4*)(p + 4);
            xr[r][0] = v0.x; xr[r][1] = v0.y; xr[r][2] = v0.z; xr[r][3] = v0.w;
            xr[r][4] = v1.x; xr[r][5] = v1.y; xr[r][6] = v1.z; xr[r][7] = v1.w;
        }
        if (WRXB) {
#pragma unroll
            for (int r = 0; r < 4; ++r) {
                bf16x8 v;
#pragma unroll
                for (int j = 0; j < 8; ++j) v[j] = (bf16_t)xr[r][j];
                *(bf16x8*)(xb + off + (size_t)r * D) = v;
            }
        }
        float d[4] = {0.f, 0.f, 0.f, 0.f};
#pragma unroll
        for (int j = 0; j < 8; ++j) {
#pragma unroll
            for (int r = 0; r < 4; ++r) d[r] += xr[r][j] * hl[j];
        }
#pragma unroll
        for (int o = 32; o > 0; o >>= 1) {
#pragma unroll
            for (int r = 0; r < 4; ++r) d[r] += __shfl_xor(d[r], o, 64);
        }
        float mx    = fmaxf(fmaxf(d[0], d[1]), fmaxf(d[2], d[3]));
        float m_new = fmaxf(m_w, mx);
        float alpha = __expf(m_w - m_new);       // 0 on first iteration
        float p0 = __expf(d[0] - m_new), p1 = __expf(d[1] - m_new);
        float p2 = __expf(d[2] - m_new), p3 = __expf(d[3] - m_new);
        s_w = s_w * alpha + ((p0 + p1) + (p2 + p3));
#pragma unroll
        for (int j = 0; j < 8; ++j)
            r_w[j] = r_w[j] * alpha + p0 * xr[0][j] + p1 * xr[1][j]
                                    + p2 * xr[2][j] + p3 * xr[3][j];
        m_w = m_new;
    }
    if (i < cnt) {                               // tail: 1..3 rows
        int rem = cnt - i;
        size_t off = (((size_t)(s + i)) << 9) + (size_t)(lane * 8);
        float xr[4][8];
#pragma unroll
        for (int r = 0; r < 4; ++r) {
            if (r < rem) {
                const float* p = xp + off + (size_t)r * D;
                float4 v0 = *(const float4*)p;
                float4 v1 = *(const float4*)(p + 4);
                xr[r][0] = v0.x; xr[r][1] = v0.y; xr[r][2] = v0.z; xr[r][3] = v0.w;
                xr[r][4] = v1.x; xr[r][5] = v1.y; xr[r][6] = v1.z; xr[r][7] = v1.w;
            } else {
#pragma unroll
                for (int j = 0; j < 8; ++j) xr[r][j] = 0.f;
            }
        }
        if (WRXB) {
#pragma unroll
            for (int r = 0; r < 4; ++r) {
                if (r < rem) {
                    bf16x8 v;
#pragma unroll
                    for (int j = 0; j < 8; ++j) v[j] = (bf16_t)xr[r][j];
                    *(bf16x8*)(xb + off + (size_t)r * D) = v;
                }
            }
        }
        float d[4] = {0.f, 0.f, 0.f, 0.f};
#pragma unroll
        for (int j = 0; j < 8; ++j) {
#pragma unroll
            for (int r = 0; r < 4; ++r) d[r] += xr[r][j] * hl[j];
        }
#pragma unroll
        for (int o = 32; o > 0; o >>= 1) {
#pragma unroll
            for (int r = 0; r < 4; ++r) d[r] += __shfl_xor(d[r], o, 64);
        }
#pragma unroll
        for (int r = 0; r < 4; ++r)
            if (r >= rem) d[r] = -INFINITY;
        float mx    = fmaxf(fmaxf(d[0], d[1]), fmaxf(d[2], d[3]));
        float m_new = fmaxf(m_w, mx);            // finite: rem >= 1
        float alpha = __expf(m_w - m_new);
        float p0 = __expf(d[0] - m_new), p1 = __expf(d[1] - m_new);
        float p2 = __expf(d[2] - m_new), p3 = __expf(d[3] - m_new);
        s_w = s_w * alpha + ((p0 + p1) + (p2 + p3));
#pragma unroll
        for (int j = 0; j < 8; ++j)
            r_w[j] = r_w[j] * alpha + p0 * xr[0][j] + p1 * xr[1][j]
                                    + p2 * xr[2][j] + p3 * xr[3][j];
        m_w = m_new;
    }
}

// bf16 input (either cached xb or native-bf16 x).
__device__ __forceinline__ void scan_bf16(const bf16_t* __restrict__ xp,
                                          int s, int cnt, int wave, int lane,
                                          const float* hl,
                                          float& m_w, float& s_w, float* r_w) {
    int i = 4 * wave;
    for (; i + 4 <= cnt; i += 4 * AWAVES) {
        size_t off = (((size_t)(s + i)) << 9) + (size_t)(lane * 8);
        float xr[4][8];
#pragma unroll
        for (int r = 0; r < 4; ++r) {
            bf16x8 v = *(const bf16x8*)(xp + off + (size_t)r * D);
#pragma unroll
            for (int j = 0; j < 8; ++j) xr[r][j] = (float)v[j];
        }
        float d[4] = {0.f, 0.f, 0.f, 0.f};
#pragma unroll
        for (int j = 0; j < 8; ++j) {
#pragma unroll
            for (int r = 0; r < 4; ++r) d[r] += xr[r][j] * hl[j];
        }
#pragma unroll
        for (int o = 32; o > 0; o >>= 1) {
#pragma unroll
            for (int r = 0; r < 4; ++r) d[r] += __shfl_xor(d[r], o, 64);
        }
        float mx    = fmaxf(fmaxf(d[0], d[1]), fmaxf(d[2], d[3]));
        float m_new = fmaxf(m_w, mx);
        float alpha = __expf(m_w - m_new);
        float p0 = __expf(d[0] - m_new), p1 = __expf(d[1] - m_new);
        float p2 = __expf(d[2] - m_new), p3 = __expf(d[3] - m_new);
        s_w = s_w * alpha + ((p0 + p1) + (p2 + p3));
#pragma unroll
        for (int j = 0; j < 8; ++j)
            r_w[j] = r_w[j] * alpha + p0 * xr[0][j] + p1 * xr[1][j]
                                    + p2 * xr[2][j] + p3 * xr[3][j];
        m_w = m_new;
    }
    if (i < cnt) {
        int rem = cnt - i;
        size_t off = (((size_t)(s + i)) << 9) + (size_t)(lane * 8);
        float xr[4][8];
#pragma unroll
        for (int r = 0; r < 4; ++r) {
            if (r < rem) {
                bf16x8 v = *(const bf16x8*)(xp + off + (size_t)r * D);
#pragma unroll
                for (int j = 0; j < 8; ++j) xr[r][j] = (float)v[j];
            } else {
#pragma unroll
                for (int j = 0; j < 8; ++j) xr[r][j] = 0.f;
            }
        }
        float d[4] = {0.f, 0.f, 0.f, 0.f};
#pragma unroll
        for (int j = 0; j < 8; ++j) {
#pragma unroll
            for (int r = 0; r < 4; ++r) d[r] += xr[r][j] * hl[j];
        }
#pragma unroll
        for (int o = 32; o > 0; o >>= 1) {
#pragma unroll
            for (int r = 0; r < 4; ++r) d[r] += __shfl_xor(d[r], o, 64);
        }
#pragma unroll
        for (int r = 0; r < 4; ++r)
            if (r >= rem) d[r] = -INFINITY;
        float mx    = fmaxf(fmaxf(d[0], d[1]), fmaxf(d[2], d[3]));
        float m_new = fmaxf(m_w, mx);
        float alpha = __expf(m_w - m_new);
        float p0 = __expf(d[0] - m_new), p1 = __expf(d[1] - m_new);
        float p2 = __expf(d[2] - m_new), p3 = __expf(d[3] - m_new);
        s_w = s_w * alpha + ((p0 + p1) + (p2 + p3));
#pragma unroll
        for (int j = 0; j < 8; ++j)
            r_w[j] = r_w[j] * alpha + p0 * xr[0][j] + p1 * xr[1][j]
                                    + p2 * xr[2][j] + p3 * xr[3][j];
        m_w = m_new;
    }
}

// ---------------------------------------------------------------------------
// Fused flash-style segment softmax attention: one block (16 waves) per graph,
// ONE pass over x, 4 nodes per wave-iteration.  STEP0/USE_XB are host-known
// template params; only the fp32-ness of the input is a device-side flag, and
// it selects between two fully-unswitched branch-free loops.
template<int STEP0, int USE_XB>
__global__ __launch_bounds__(1024)
void attention_kernel(const void* __restrict__ x, bf16_t* __restrict__ xb,
                      int N, const int* __restrict__ seg,
                      const float* __restrict__ hbuf,
                      bf16_t* __restrict__ AbufOut,
                      const int* __restrict__ flags) {
    __shared__ float racc2[AWAVES][D];     // 32 KiB
    __shared__ float red_m[AWAVES], red_s[AWAVES];

    const int f32x = flags[1];

    const int b = blockIdx.x;
    int s  = seg[b];
    int en = seg[b + 1];
    s  = (s  < 0) ? 0 : ((s  > N) ? N : s);     // defensive clamp
    en = (en < s) ? s : ((en > N) ? N : en);
    const int cnt  = en - s;
    const int tid  = threadIdx.x;
    const int wave = tid >> 6;
    const int lane = tid & 63;

    // per-lane slice of h (8 contiguous f32); same for all waves -> L1 hot
    float hl[8];
    {
        const float* hp = hbuf + ((size_t)b << 9) + lane * 8;
#pragma unroll
        for (int j = 0; j < 8; ++j) hl[j] = hp[j];
    }

    float m_w = -INFINITY, s_w = 0.f;
    float r_w[8];
#pragma unroll
    for (int j = 0; j < 8; ++j) r_w[j] = 0.f;

    if (f32x) {
        if (STEP0 || !USE_XB) {
            // fp32 read; fused bf16 cast only in step0 when xb exists
            scan_f32<(STEP0 && USE_XB)>((const float*)x, xb, s, cnt,
                                        wave, lane, hl, m_w, s_w, r_w);
        } else {
            scan_bf16(xb, s, cnt, wave, lane, hl, m_w, s_w, r_w);
        }
    } else {
        scan_bf16((const bf16_t*)x, s, cnt, wave, lane, hl, m_w, s_w, r_w);
    }

    if (lane == 0) { red_m[wave] = m_w; red_s[wave] = s_w; }
    __syncthreads();

    float M = -INFINITY, S = 0.f;
#pragma unroll
    for (int w = 0; w < AWAVES; ++w)
        if (red_s[w] > 0.f) M = fmaxf(M, red_m[w]);
#pragma unroll
    for (int w = 0; w < AWAVES; ++w)
        if (red_s[w] > 0.f) S += red_s[w] * __expf(red_m[w] - M);
    float Sinv  = 1.f / (S + 1e-16f);
    float scale = (s_w > 0.f) ? __expf(m_w - M) * Sinv : 0.f;

#pragma unroll
    for (int j = 0; j < 8; ++j) racc2[wave][lane * 8 + j] = r_w[j] * scale;
    __syncthreads();

    if (tid < D) {
        float r = 0.f;
#pragma unroll
        for (int w = 0; w < AWAVES; ++w) r += racc2[w][tid];
        AbufOut[(size_t)b * KCAT + 512 + tid] = (bf16_t)r;  // r -> cols [512,1024)
    }
}

// ---------------------------------------------------------------------------
// out = q_star @ W_proj^T + b_proj.  M=256 graphs, N=256, K=1024 (lda=KCAT).
__global__ __launch_bounds__(64)
void gemm_proj(const bf16_t* __restrict__ A,
               const bf16_t* __restrict__ Wp, const float* __restrict__ bp,
               void* __restrict__ out, const int* __restrict__ flags) {
    const int f32o  = flags[1];
    const int lane  = threadIdx.x;
    const int n0    = blockIdx.x * 16;
    const int m0    = blockIdx.y * 16;
    const int rowA  = m0 + (lane & 15);
    const int rowB  = n0 + (lane & 15);
    const int kbase = (lane >> 4) * 8;

    f32x4 acc = {0.f, 0.f, 0.f, 0.f};
    for (int k0 = 0; k0 < 1024; k0 += 32) {
        int k = k0 + kbase;
        bf16x8 a = *(const bf16x8*)(A  + (size_t)rowA * KCAT + k);
        bf16x8 b = *(const bf16x8*)(Wp + (size_t)rowB * 1024 + k);
        acc = __builtin_amdgcn_mfma_f32_16x16x32_bf16(a, b, acc, 0, 0, 0);
    }
    const int col   = n0 + (lane & 15);
    const int rbase = (lane >> 4) * 4;
    float bias = bp[col];
#pragma unroll
    for (int r = 0; r < 4; ++r) {
        int m = m0 + rbase + r;
        float v = acc[r] + bias;
        if (f32o) ((float*)out)[(size_t)m * 256 + col]  = v;
        else      ((bf16_t*)out)[(size_t)m * 256 + col] = (bf16_t)v;
    }
}

// ---------------------------------------------------------------------------
extern "C" void kernel_launch(void* const* d_in, const int* in_sizes, int n_in,
                              void* d_out, int out_size, void* d_ws, size_t ws_size,
                              hipStream_t stream) {
    const void* x      = d_in[0];
    const void* batch  = d_in[1];
    const void* W_ih   = d_in[2];
    const void* W_hh   = d_in[3];
    const void* b_ih   = d_in[4];
    const void* b_hh   = d_in[5];
    const void* W_proj = d_in[6];
    const void* b_proj = d_in[7];

    const int N = in_sizes[1];          // 100000 nodes
    const int B = B_GR;                 // 256 graphs

    // workspace carve-up (1 KiB aligned); nothing read before written in-call
    char* p = (char*)d_ws;
    size_t used = 0;
    auto carve = [&](size_t bytes) {
        void* r = (void*)p;
        size_t a = (bytes + 1023) & ~(size_t)1023;
        p += a;
        used += a;
        return r;
    };
    float*  c_buf = (float*)carve((size_t)B * D * 4);
    float*  h_buf = (float*)carve((size_t)B * D * 4);
    bf16_t* Abuf0 = (bf16_t*)carve((size_t)B * KCAT * 2);
    bf16_t* Abuf1 = (bf16_t*)carve((size_t)B * KCAT * 2);
    bf16_t* Wcat  = (bf16_t*)carve((size_t)FOURD * KCAT * 2);  // 6 MiB
    bf16_t* Wp    = (bf16_t*)carve((size_t)256 * 1024 * 2);
    float*  bsum  = (float*)carve((size_t)FOURD * 4);
    float*  bp    = (float*)carve((size_t)256 * 4);
    int*    seg   = (int*)carve((size_t)(B + 1) * 4);
    int*    flags = (int*)carve(8);
    int*    partA = (int*)carve(DET_BLOCKS * 4);
    int*    partB = (int*)carve(DET_BLOCKS * 4);
    if (used > ws_size) return;
    bf16_t* xb = (bf16_t*)carve((size_t)N * D * 2);            // ~100 MiB
    int use_xb = (used <= ws_size) ? 1 : 0;

    detect_part1<<<DET_BLOCKS, 256, 0, stream>>>(
        (const int*)batch, N, (const unsigned short*)x, partA, partB);
    detect_part2<<<1, 512, 0, stream>>>(partA, partB, DET_BLOCKS, flags);
    seg_bounds_kernel<<<(N + 255) / 256, 256, 0, stream>>>(batch, N, B, flags, seg);
    prep_kernel<<<1024, 256, 0, stream>>>(W_ih, W_hh, b_ih, b_hh, W_proj, b_proj,
                                          flags, Wcat, Wp, bsum, bp);

    // step 0: specialized LSTM (no GEMM), attention fused with x->bf16 cast
    lstm0_kernel<<<(B * D) / 256, 256, 0, stream>>>(bsum, c_buf, h_buf, Abuf0);
    if (use_xb)
        attention_kernel<1, 1><<<B, 1024, 0, stream>>>(x, xb, N, seg,
                                                       h_buf, Abuf0, flags);
    else
        attention_kernel<1, 0><<<B, 1024, 0, stream>>>(x, xb, N, seg,
                                                       h_buf, Abuf0, flags);

    // step 1
    gemm_lstm<<<dim3(D / 16, B / 16), 64, 0, stream>>>(
        Abuf0, Wcat, bsum, c_buf, h_buf, Abuf1);
    if (use_xb)
        attention_kernel<0, 1><<<B, 1024, 0, stream>>>(x, xb, N, seg,
                                                       h_buf, Abuf1, flags);
    else
        attention_kernel<0, 0><<<B, 1024, 0, stream>>>(x, xb, N, seg,
                                                       h_buf, Abuf1, flags);
    // step 2
    gemm_lstm<<<dim3(D / 16, B / 16), 64, 0, stream>>>(
        Abuf1, Wcat, bsum, c_buf, h_buf, Abuf0);
    if (use_xb)
        attention_kernel<0, 1><<<B, 1024, 0, stream>>>(x, xb, N, seg,
                                                       h_buf, Abuf0, flags);
    else
        attention_kernel<0, 0><<<B, 1024, 0, stream>>>(x, xb, N, seg,
                                                       h_buf, Abuf0, flags);

    // projection
    gemm_proj<<<dim3(256 / 16, B / 16), 64, 0, stream>>>(Abuf0, Wp, bp, d_out, flags);
}